// Round 6
// baseline (81.099 us; speedup 1.0000x reference)
//
#include <hip/hip_runtime.h>
#include <hip/hip_bf16.h>
#include <math.h>

// Problem constants
#define BB 2
#define HH 64
#define WW 64
#define CC 128
#define NHD 4
#define HD 32
#define KS 7
#define KK 49
#define HID 512
#define NT (BB*HH*WW)   // 8192 tokens

typedef __attribute__((ext_vector_type(8))) short bf16x8;
typedef __attribute__((ext_vector_type(4))) float f32x4;

__device__ __forceinline__ short f2bs(float v) {
    __hip_bfloat16 h = __float2bfloat16(v);
    return *reinterpret_cast<short*>(&h);
}

// ---------------- prep: weight cast/transpose W[K][N] f32 -> Wt[N][K] bf16 ------
__global__ void prep_cast(const float* __restrict__ qkv_w, const float* __restrict__ proj_w,
                          const float* __restrict__ fc1_w, const float* __restrict__ fc2_w,
                          __hip_bfloat16* __restrict__ qkv_wt, __hip_bfloat16* __restrict__ proj_wt,
                          __hip_bfloat16* __restrict__ fc1_wt, __hip_bfloat16* __restrict__ fc2_wt) {
    int idx = blockIdx.x * 256 + threadIdx.x;
    const float* W; __hip_bfloat16* Wt; int K, N, off;
    if (idx < 49152)       { W = qkv_w;  Wt = qkv_wt;  K = 128; N = 384; off = idx; }
    else if (idx < 65536)  { W = proj_w; Wt = proj_wt; K = 128; N = 128; off = idx - 49152; }
    else if (idx < 131072) { W = fc1_w;  Wt = fc1_wt;  K = 128; N = 512; off = idx - 65536; }
    else                   { W = fc2_w;  Wt = fc2_wt;  K = 512; N = 128; off = idx - 131072; }
    int k = off / N, n = off - k * N;
    Wt[(size_t)n * K + k] = __float2bfloat16(W[(size_t)k * N + n]);
}

// ---------------- LN-fused MFMA GEMM (K=128): out = LN(A) @ Wt^T + bias ---------
// Block: 64 output rows x 64 cols, 256 threads (4 waves, 2x2).
// Phase 1: LN of 64 rows of f32 A into swizzled bf16 LDS tile.
// Phase 2: MFMA from LDS (A) and global (Wt).
template<int OUT_BF16, int DO_GELU>
__global__ void mfma_gemm_ln(const float* __restrict__ Araw,
                             const float* __restrict__ gamma, const float* __restrict__ beta,
                             const __hip_bfloat16* __restrict__ Wt,
                             const float* __restrict__ bias,
                             void* __restrict__ out, int N) {
    __shared__ bf16x8 As[64 * 16];      // 64 rows x 16 chunks(16B) = 16 KB, swizzled
    int tid = threadIdx.x;

    // ---- Phase 1: LayerNorm 64 rows; 4 threads per row, 32 f32 each ----
    {
        int rl = tid >> 2;              // local row 0..63
        int q  = tid & 3;               // quarter
        const float* ar = Araw + ((size_t)blockIdx.x * 64 + rl) * CC + q * 32;
        float4 xv[8];
        float s1 = 0.f, s2 = 0.f;
        #pragma unroll
        for (int t = 0; t < 8; ++t) {
            xv[t] = ((const float4*)ar)[t];
            s1 += xv[t].x + xv[t].y + xv[t].z + xv[t].w;
            s2 += xv[t].x * xv[t].x + xv[t].y * xv[t].y + xv[t].z * xv[t].z + xv[t].w * xv[t].w;
        }
        s1 += __shfl_xor(s1, 1); s1 += __shfl_xor(s1, 2);
        s2 += __shfl_xor(s2, 1); s2 += __shfl_xor(s2, 2);
        float mean = s1 * (1.0f / CC);
        float var  = s2 * (1.0f / CC) - mean * mean;
        float rstd = rsqrtf(var + 1e-5f);
        #pragma unroll
        for (int cc = 0; cc < 4; ++cc) {
            int colbase = q * 32 + cc * 8;
            float4 aa = xv[2 * cc], bb = xv[2 * cc + 1];
            float4 g0 = *(const float4*)(gamma + colbase);
            float4 g1 = *(const float4*)(gamma + colbase + 4);
            float4 b0 = *(const float4*)(beta + colbase);
            float4 b1 = *(const float4*)(beta + colbase + 4);
            bf16x8 ch;
            ch[0] = f2bs((aa.x - mean) * rstd * g0.x + b0.x);
            ch[1] = f2bs((aa.y - mean) * rstd * g0.y + b0.y);
            ch[2] = f2bs((aa.z - mean) * rstd * g0.z + b0.z);
            ch[3] = f2bs((aa.w - mean) * rstd * g0.w + b0.w);
            ch[4] = f2bs((bb.x - mean) * rstd * g1.x + b1.x);
            ch[5] = f2bs((bb.y - mean) * rstd * g1.y + b1.y);
            ch[6] = f2bs((bb.z - mean) * rstd * g1.z + b1.z);
            ch[7] = f2bs((bb.w - mean) * rstd * g1.w + b1.w);
            As[rl * 16 + (((q << 2) | cc) ^ (rl & 15))] = ch;
        }
    }

    // ---- Phase 2: MFMA ----
    int wid = tid >> 6, lane = tid & 63;
    int wr = wid >> 1, wc = wid & 1;
    int m0l = wr * 32;                     // local row base
    int n0 = blockIdx.y * 64 + wc * 32;
    int rowf = lane & 15, kg = lane >> 4;

    bf16x8 b[2][4];
    #pragma unroll
    for (int ni = 0; ni < 2; ++ni)
        #pragma unroll
        for (int t = 0; t < 4; ++t)
            b[ni][t] = *(const bf16x8*)(Wt + (size_t)(n0 + ni * 16 + rowf) * CC + t * 32 + kg * 8);

    __syncthreads();

    bf16x8 a[2][4];
    #pragma unroll
    for (int mi = 0; mi < 2; ++mi) {
        int rl2 = m0l + mi * 16 + rowf;
        #pragma unroll
        for (int t = 0; t < 4; ++t)
            a[mi][t] = As[rl2 * 16 + (((t << 2) | kg) ^ (rl2 & 15))];
    }

    f32x4 acc[2][2] = {};
    #pragma unroll
    for (int t = 0; t < 4; ++t)
        #pragma unroll
        for (int mi = 0; mi < 2; ++mi)
            #pragma unroll
            for (int ni = 0; ni < 2; ++ni)
                acc[mi][ni] = __builtin_amdgcn_mfma_f32_16x16x32_bf16(a[mi][t], b[ni][t], acc[mi][ni], 0, 0, 0);

    #pragma unroll
    for (int mi = 0; mi < 2; ++mi) {
        #pragma unroll
        for (int ni = 0; ni < 2; ++ni) {
            int col = n0 + ni * 16 + rowf;
            float bv = bias[col];
            #pragma unroll
            for (int r = 0; r < 4; ++r) {
                int rrow = blockIdx.x * 64 + m0l + mi * 16 + kg * 4 + r;
                float v = acc[mi][ni][r] + bv;
                if (DO_GELU) v = 0.5f * v * (1.0f + erff(v * 0.70710678118654752f));
                size_t off = (size_t)rrow * N + col;
                if (OUT_BF16) ((__hip_bfloat16*)out)[off] = __float2bfloat16(v);
                else          ((float*)out)[off] = v;
            }
        }
    }
}

// ---------------- MFMA GEMM (bf16 A in global): out = A @ Wt^T + bias [+resid] ---
template<int TK, int OUT_BF16, int DO_GELU, int HAS_RESID>
__global__ void mfma_gemm(const __hip_bfloat16* __restrict__ A,
                          const __hip_bfloat16* __restrict__ Wt,
                          const float* __restrict__ bias,
                          const float* __restrict__ resid,
                          void* __restrict__ out,
                          int M, int N) {
    int wid  = threadIdx.x >> 6;
    int lane = threadIdx.x & 63;
    int wr = wid >> 1, wc = wid & 1;
    int m0 = blockIdx.x * 64 + wr * 32;
    int n0 = blockIdx.y * 64 + wc * 32;
    int row = lane & 15;
    int kg  = lane >> 4;

    f32x4 acc[2][2] = {};
    #pragma unroll
    for (int kc = 0; kc < TK; kc += 128) {
        bf16x8 a[2][4], b[2][4];
        #pragma unroll
        for (int mi = 0; mi < 2; ++mi)
            #pragma unroll
            for (int t = 0; t < 4; ++t)
                a[mi][t] = *(const bf16x8*)(A + (size_t)(m0 + mi * 16 + row) * TK + kc + t * 32 + kg * 8);
        #pragma unroll
        for (int ni = 0; ni < 2; ++ni)
            #pragma unroll
            for (int t = 0; t < 4; ++t)
                b[ni][t] = *(const bf16x8*)(Wt + (size_t)(n0 + ni * 16 + row) * TK + kc + t * 32 + kg * 8);
        #pragma unroll
        for (int t = 0; t < 4; ++t)
            #pragma unroll
            for (int mi = 0; mi < 2; ++mi)
                #pragma unroll
                for (int ni = 0; ni < 2; ++ni)
                    acc[mi][ni] = __builtin_amdgcn_mfma_f32_16x16x32_bf16(a[mi][t], b[ni][t], acc[mi][ni], 0, 0, 0);
    }
    #pragma unroll
    for (int mi = 0; mi < 2; ++mi) {
        #pragma unroll
        for (int ni = 0; ni < 2; ++ni) {
            int col = n0 + ni * 16 + row;
            float bv = bias[col];
            #pragma unroll
            for (int r = 0; r < 4; ++r) {
                int rrow = m0 + mi * 16 + kg * 4 + r;
                float v = acc[mi][ni][r] + bv;
                if (DO_GELU) v = 0.5f * v * (1.0f + erff(v * 0.70710678118654752f));
                size_t off = (size_t)rrow * N + col;
                if (HAS_RESID) v += resid[off];
                if (OUT_BF16) ((__hip_bfloat16*)out)[off] = __float2bfloat16(v);
                else          ((float*)out)[off] = v;
            }
        }
    }
}

// ---------------- Neighborhood attention (bf16 qkv): one WAVE per (token, head) --
__device__ __forceinline__ float4 bf4_to_f4(ushort4 u) {
    float4 f;
    f.x = __uint_as_float((unsigned)u.x << 16);
    f.y = __uint_as_float((unsigned)u.y << 16);
    f.z = __uint_as_float((unsigned)u.z << 16);
    f.w = __uint_as_float((unsigned)u.w << 16);
    return f;
}

__global__ void nat_attn_wave8(const __hip_bfloat16* __restrict__ qkv,
                               const float* __restrict__ rpb,
                               __hip_bfloat16* __restrict__ out) {
    int h    = threadIdx.x >> 6;       // wave id = head
    int lane = threadIdx.x & 63;
    int kq = lane >> 3, dg = lane & 7;
    int bij = blockIdx.x;
    int j  = bij & (WW - 1);
    int bi = bij >> 6;
    int i  = bi & (HH - 1);
    int b  = bi >> 6;

    int si = i - 3; si = si < 0 ? 0 : (si > HH - KS ? HH - KS : si);
    int sj = j - 3; sj = sj < 0 ? 0 : (sj > WW - KS ? WW - KS : sj);
    int oi = si - i + 6;
    int oj = sj - j + 6;

    float4 q4 = bf4_to_f4(*(const ushort4*)(qkv + (size_t)bij * (3 * CC) + h * HD + dg * 4));
    const float sc = 0.17677669529663687f;  // 1/sqrt(32)
    q4.x *= sc; q4.y *= sc; q4.z *= sc; q4.w *= sc;
    const float* rpb_h = rpb + h * 169;     // 13x13

    float s[7];
    float4 v4[7];
    #pragma unroll
    for (int t = 0; t < 7; ++t) {
        int kk = t * 8 + kq;
        bool valid = kk < KK;
        int a = (kk * 37) >> 8;             // kk/7 for kk<56
        int c = kk - a * 7;
        if (!valid) { a = 0; c = 0; }
        int ki = si + a, kj = sj + c;
        const __hip_bfloat16* base = qkv + ((size_t)((b * HH + ki) * WW + kj)) * (3 * CC) + h * HD + dg * 4;
        float4 k4 = bf4_to_f4(*(const ushort4*)(base + CC));
        v4[t]     = bf4_to_f4(*(const ushort4*)(base + 2 * CC));
        float pd = q4.x * k4.x + q4.y * k4.y + q4.z * k4.z + q4.w * k4.w;
        pd += __shfl_xor(pd, 1);
        pd += __shfl_xor(pd, 2);
        pd += __shfl_xor(pd, 4);
        s[t] = valid ? (pd + rpb_h[(oi + a) * 13 + (oj + c)]) : -1e30f;
    }
    float mx = s[0];
    #pragma unroll
    for (int t = 1; t < 7; ++t) mx = fmaxf(mx, s[t]);
    mx = fmaxf(mx, __shfl_xor(mx, 8));
    mx = fmaxf(mx, __shfl_xor(mx, 16));
    mx = fmaxf(mx, __shfl_xor(mx, 32));
    float l = 0.0f;
    #pragma unroll
    for (int t = 0; t < 7; ++t) { s[t] = __expf(s[t] - mx); l += s[t]; }
    l += __shfl_xor(l, 8);
    l += __shfl_xor(l, 16);
    l += __shfl_xor(l, 32);
    float inv = 1.0f / l;

    float4 o4 = make_float4(0.f, 0.f, 0.f, 0.f);
    #pragma unroll
    for (int t = 0; t < 7; ++t) {
        o4.x += s[t] * v4[t].x;
        o4.y += s[t] * v4[t].y;
        o4.z += s[t] * v4[t].z;
        o4.w += s[t] * v4[t].w;
    }
    #pragma unroll
    for (int off = 8; off <= 32; off <<= 1) {
        o4.x += __shfl_xor(o4.x, off);
        o4.y += __shfl_xor(o4.y, off);
        o4.z += __shfl_xor(o4.z, off);
        o4.w += __shfl_xor(o4.w, off);
    }
    if (kq == 0) {
        __hip_bfloat16 r0 = __float2bfloat16(o4.x * inv);
        __hip_bfloat16 r1 = __float2bfloat16(o4.y * inv);
        __hip_bfloat16 r2 = __float2bfloat16(o4.z * inv);
        __hip_bfloat16 r3 = __float2bfloat16(o4.w * inv);
        ushort4 u;
        u.x = *(unsigned short*)&r0;
        u.y = *(unsigned short*)&r1;
        u.z = *(unsigned short*)&r2;
        u.w = *(unsigned short*)&r3;
        *(ushort4*)(out + (size_t)bij * CC + h * HD + dg * 4) = u;
    }
}

extern "C" void kernel_launch(void* const* d_in, const int* in_sizes, int n_in,
                              void* d_out, int out_size, void* d_ws, size_t ws_size,
                              hipStream_t stream) {
    const float* x       = (const float*)d_in[0];
    const float* norm1_g = (const float*)d_in[1];
    const float* norm1_b = (const float*)d_in[2];
    const float* qkv_w   = (const float*)d_in[3];
    const float* qkv_b   = (const float*)d_in[4];
    const float* rpb     = (const float*)d_in[5];
    const float* proj_w  = (const float*)d_in[6];
    const float* proj_b  = (const float*)d_in[7];
    const float* norm2_g = (const float*)d_in[8];
    const float* norm2_b = (const float*)d_in[9];
    const float* fc1_w   = (const float*)d_in[10];
    const float* fc1_b   = (const float*)d_in[11];
    const float* fc2_w   = (const float*)d_in[12];
    const float* fc2_b   = (const float*)d_in[13];
    float* out = (float*)d_out;

    char* ws = (char*)d_ws;
    // workspace layout (bytes):
    //   qkv   bf16: [0, 6291456)     dead after attention; h1 reuses [0, 8388608)
    //   attn  bf16: [14680064, 16777216)
    //   x1    f32 : [16777216, 20971520)
    //   wts   bf16: [23068672, ...)
    __hip_bfloat16* qkv  = (__hip_bfloat16*)(ws);
    __hip_bfloat16* h1   = (__hip_bfloat16*)(ws);
    __hip_bfloat16* attn = (__hip_bfloat16*)(ws + 14680064);
    float* x1            = (float*)(ws + 16777216);
    __hip_bfloat16* qkv_wt  = (__hip_bfloat16*)(ws + 23068672);  // 384x128
    __hip_bfloat16* proj_wt = qkv_wt + 384 * 128;                // 128x128
    __hip_bfloat16* fc1_wt  = proj_wt + 128 * 128;               // 512x128
    __hip_bfloat16* fc2_wt  = fc1_wt + 512 * 128;                // 128x512

    // 0) weight casts
    prep_cast<<<768, 256, 0, stream>>>(qkv_w, proj_w, fc1_w, fc2_w,
                                       qkv_wt, proj_wt, fc1_wt, fc2_wt);
    // 1) LN1 + QKV GEMM: (8192x128)@(128x384) -> bf16
    {
        dim3 grid(NT / 64, 384 / 64);
        mfma_gemm_ln<1, 0><<<grid, 256, 0, stream>>>(x, norm1_g, norm1_b,
                                                     qkv_wt, qkv_b, qkv, 3 * CC);
    }
    // 2) NAT attention -> bf16
    nat_attn_wave8<<<NT, 256, 0, stream>>>(qkv, rpb, attn);
    // 3) proj + bias + residual(x) -> f32 x1
    {
        dim3 grid(NT / 64, CC / 64);
        mfma_gemm<128, 0, 0, 1><<<grid, 256, 0, stream>>>(attn, proj_wt, proj_b, x, x1,
                                                          NT, CC);
    }
    // 4) LN2 + FC1 + gelu -> bf16
    {
        dim3 grid(NT / 64, HID / 64);
        mfma_gemm_ln<1, 1><<<grid, 256, 0, stream>>>(x1, norm2_g, norm2_b,
                                                     fc1_wt, fc1_b, h1, HID);
    }
    // 5) FC2 + bias + residual(x1) -> f32 out
    {
        dim3 grid(NT / 64, CC / 64);
        mfma_gemm<512, 0, 0, 1><<<grid, 256, 0, stream>>>(h1, fc2_wt, fc2_b, x1, out,
                                                          NT, CC);
    }
}